// Round 1
// baseline (145.233 us; speedup 1.0000x reference)
//
#include <hip/hip_runtime.h>
#include <hip/hip_bf16.h>
#include <math.h>

using f32x4 = __attribute__((ext_vector_type(4))) float;
using s16x8 = __attribute__((ext_vector_type(8))) short;
using s16x4 = __attribute__((ext_vector_type(4))) short;

__device__ __forceinline__ unsigned short f2bf(float f) {
  unsigned int u = __builtin_bit_cast(unsigned int, f);
  u += 0x7FFFu + ((u >> 16) & 1u);
  return (unsigned short)(u >> 16);
}
__device__ __forceinline__ float bf2f(unsigned short h) {
  unsigned int u = ((unsigned int)h) << 16;
  return __builtin_bit_cast(float, u);
}
__device__ __forceinline__ float lrelu(float v) { return v > 0.f ? v : 0.01f * v; }

// ---------------------------------------------------------------------------
// Kernel 1: x1t[n][c], x2t[n][c], x3[c][n]  (bf16) = lrelu(Wi @ x + bi)
// grid 256 (b*64 + nchunk), block 256. Each block: one batch, 64 n-columns.
// ---------------------------------------------------------------------------
__global__ __launch_bounds__(256) void k1_conv3(
    const float* __restrict__ x,
    const float* __restrict__ W1, const float* __restrict__ b1,
    const float* __restrict__ W2, const float* __restrict__ b2,
    const float* __restrict__ W3, const float* __restrict__ b3,
    unsigned short* __restrict__ x1t, unsigned short* __restrict__ x2t,
    unsigned short* __restrict__ x3) {
  __shared__ float Wt[3][64][65];          // Wt[w][k][c] = W[c][k]
  __shared__ alignas(16) float sX[64][68]; // sX[k][n']
  __shared__ unsigned short sB[64][68];    // bounce for x3 transpose
  const int t = threadIdx.x;
  const int b = blockIdx.x >> 6;
  const int n0 = (blockIdx.x & 63) << 6;

  const float* Ws[3] = {W1, W2, W3};
#pragma unroll
  for (int w = 0; w < 3; ++w)
    for (int e = t; e < 4096; e += 256)
      Wt[w][e & 63][e >> 6] = Ws[w][(e >> 6) * 64 + (e & 63)];
  {
    const int k = t >> 2, q = t & 3;
    const float4* src = (const float4*)(x + ((size_t)b * 64 + k) * 4096 + n0 + q * 16);
#pragma unroll
    for (int j = 0; j < 4; ++j) *(float4*)&sX[k][q * 16 + 4 * j] = src[j];
  }
  __syncthreads();

  const int c = t & 63, g = t >> 6; // this thread: out-channel c, n' = g*16+j
  float y1[16], y2[16], y3[16];
  const float bb1 = b1[c], bb2 = b2[c], bb3 = b3[c];
#pragma unroll
  for (int j = 0; j < 16; ++j) { y1[j] = bb1; y2[j] = bb2; y3[j] = bb3; }

  for (int k = 0; k < 64; ++k) {
    const float w1 = Wt[0][k][c], w2 = Wt[1][k][c], w3 = Wt[2][k][c];
#pragma unroll
    for (int q = 0; q < 4; ++q) {
      const float4 xv = *(const float4*)&sX[k][g * 16 + q * 4];
#pragma unroll
      for (int jj = 0; jj < 4; ++jj) {
        const int j = q * 4 + jj;
        const float xs = ((const float*)&xv)[jj];
        y1[j] = __builtin_fmaf(w1, xs, y1[j]);
        y2[j] = __builtin_fmaf(w2, xs, y2[j]);
        y3[j] = __builtin_fmaf(w3, xs, y3[j]);
      }
    }
  }
  // x1t/x2t: [b][n][c] — lanes are consecutive c -> coalesced 128B rows
#pragma unroll
  for (int j = 0; j < 16; ++j) {
    const size_t n = (size_t)n0 + g * 16 + j;
    x1t[((size_t)b * 4096 + n) * 64 + c] = f2bf(lrelu(y1[j]));
    x2t[((size_t)b * 4096 + n) * 64 + c] = f2bf(lrelu(y2[j]));
  }
  // x3: [b][c][n] via LDS bounce for coalesced stores
#pragma unroll
  for (int j = 0; j < 16; ++j) sB[c][g * 16 + j] = f2bf(lrelu(y3[j]));
  __syncthreads();
  {
    const int c2 = t >> 2, q = t & 3;
    s16x8 v0, v1;
#pragma unroll
    for (int j = 0; j < 8; ++j) v0[j] = (short)sB[c2][q * 16 + j];
#pragma unroll
    for (int j = 0; j < 8; ++j) v1[j] = (short)sB[c2][q * 16 + 8 + j];
    unsigned short* dst = x3 + ((size_t)b * 64 + c2) * 4096 + n0 + q * 16;
    *(s16x8*)dst = v0;
    *(s16x8*)(dst + 8) = v1;
  }
}

// ---------------------------------------------------------------------------
// Kernel 2: fused flash attention.
//   S[n,m] = sum_c x1t[n][c]*x2t[m][c]; P = softmax_n(S); O[c,m] = sum_n x3[c][n]P[n,m]
// grid 256 (b*64 + mtile), block 256 = 4 waves; each wave owns 16 m's,
// iterates all n in 64-tiles with online softmax. MFMA 16x16x32 bf16.
// ---------------------------------------------------------------------------
__global__ __launch_bounds__(256, 1) void k2_attn(
    const unsigned short* __restrict__ x1t,
    const unsigned short* __restrict__ x2t,
    const unsigned short* __restrict__ x3,
    unsigned short* __restrict__ attn) {
  __shared__ alignas(16) unsigned short Plds[4][1024]; // per-wave P^T (16m x 64n, swizzled)
  __shared__ float sO[64][65];                         // epilogue bounce
  const int t = threadIdx.x;
  const int wave = t >> 6, lane = t & 63;
  const int l15 = lane & 15, lh = lane >> 4;
  const int b = blockIdx.x >> 6;
  const int m0 = (blockIdx.x & 63) << 6;
  const int mw = m0 + wave * 16;

  const unsigned short* x1b = x1t + (size_t)b * 4096 * 64;
  const unsigned short* x2b = x2t + (size_t)b * 4096 * 64;
  const unsigned short* x3b = x3 + (size_t)b * 64 * 4096;

  // Q fragments (B-operand): lane holds x2t[mw+l15][c0..c0+7], c0 = lh*8 (+32)
  s16x8 qf0, qf1;
  {
    const unsigned short* qp = x2b + ((size_t)(mw + l15)) * 64 + lh * 8;
    qf0 = *(const s16x8*)qp;
    qf1 = *(const s16x8*)(qp + 32);
  }

  f32x4 O[4];
#pragma unroll
  for (int s = 0; s < 4; ++s) O[s] = (f32x4){0.f, 0.f, 0.f, 0.f};
  float m_r = -INFINITY, l_r = 0.f;

  unsigned char* pb = (unsigned char*)&Plds[wave][0];
  const int swz = (l15 & 7) << 4;
  const int pw_byte = l15 * 128;

  const unsigned short* kbase = x1b + (size_t)l15 * 64 + lh * 8;
  const unsigned short* vbase = x3b + (size_t)l15 * 4096 + lh * 8;

  s16x8 kA[4][2], vA[4][2], kB[4][2], vB[4][2];

  auto loadT = [&](int nt, s16x8(&kf)[4][2], s16x8(&vf)[4][2]) {
#pragma unroll
    for (int s = 0; s < 4; ++s) { // A-frag of QK: x1t[nt+s*16+l15][lh*8 + kk*32 + i]
      const unsigned short* p = kbase + (size_t)(nt + s * 16) * 64;
      kf[s][0] = *(const s16x8*)p;
      kf[s][1] = *(const s16x8*)(p + 32);
    }
#pragma unroll
    for (int s = 0; s < 4; ++s) { // A-frag of PV: x3[s*16+l15][nt + lh*8 + kk*32 + i]
      const unsigned short* p = vbase + (size_t)s * 16 * 4096 + nt;
      vf[s][0] = *(const s16x8*)p;
      vf[s][1] = *(const s16x8*)(p + 32);
    }
  };

  auto compute = [&](s16x8(&kf)[4][2], s16x8(&vf)[4][2]) {
    // ---- S = K-tile^T Q : D[n_local, m_local], n on (reg, lh), m on l15
    f32x4 S[4];
#pragma unroll
    for (int s = 0; s < 4; ++s) {
      f32x4 z = {0.f, 0.f, 0.f, 0.f};
      z = __builtin_amdgcn_mfma_f32_16x16x32_bf16(kf[s][0], qf0, z, 0, 0, 0);
      S[s] = __builtin_amdgcn_mfma_f32_16x16x32_bf16(kf[s][1], qf1, z, 0, 0, 0);
    }
    // ---- online softmax over n (in-lane 16 + xor16 + xor32)
    float tmax = -INFINITY;
#pragma unroll
    for (int s = 0; s < 4; ++s)
#pragma unroll
      for (int r = 0; r < 4; ++r) tmax = fmaxf(tmax, S[s][r]);
    tmax = fmaxf(tmax, __shfl_xor(tmax, 16));
    tmax = fmaxf(tmax, __shfl_xor(tmax, 32));
    const float nm = fmaxf(m_r, tmax);
    const float sc = __expf(m_r - nm); // 0 on first tile
    float tsum = 0.f;
    float p[4][4];
#pragma unroll
    for (int s = 0; s < 4; ++s)
#pragma unroll
      for (int r = 0; r < 4; ++r) {
        p[s][r] = __expf(S[s][r] - nm);
        tsum += p[s][r];
      }
    tsum += __shfl_xor(tsum, 16);
    tsum += __shfl_xor(tsum, 32);
    l_r = l_r * sc + tsum;
    m_r = nm;
#pragma unroll
    for (int s = 0; s < 4; ++s) O[s] *= sc;
    // ---- P -> bf16 -> per-wave LDS (P^T[m][n], XOR-swizzled rows)
#pragma unroll
    for (int s = 0; s < 4; ++s) {
      s16x4 pk;
#pragma unroll
      for (int r = 0; r < 4; ++r) pk[r] = (short)f2bf(p[s][r]);
      const int noff2 = (s * 16 + lh * 4) * 2;
      *(s16x4*)(pb + pw_byte + (noff2 ^ swz)) = pk;
    }
    // ---- B-frags of PV: P^T[m=l15][n = kk*32 + lh*8 + i]
    s16x8 pf0 = *(const s16x8*)(pb + pw_byte + (((lh * 8) * 2) ^ swz));
    s16x8 pf1 = *(const s16x8*)(pb + pw_byte + (((32 + lh * 8) * 2) ^ swz));
#pragma unroll
    for (int s = 0; s < 4; ++s) {
      O[s] = __builtin_amdgcn_mfma_f32_16x16x32_bf16(vf[s][0], pf0, O[s], 0, 0, 0);
      O[s] = __builtin_amdgcn_mfma_f32_16x16x32_bf16(vf[s][1], pf1, O[s], 0, 0, 0);
    }
  };

  loadT(0, kA, vA);
  for (int nt = 0; nt < 4096; nt += 128) {
    loadT(nt + 64, kB, vB);
    compute(kA, vA);
    if (nt + 128 < 4096) loadT(nt + 128, kA, vA);
    compute(kB, vB);
  }

  // ---- epilogue: O /= l, bounce through LDS, coalesced bf16 store [b][c][m]
  const float inv = 1.f / l_r;
#pragma unroll
  for (int s = 0; s < 4; ++s)
#pragma unroll
    for (int r = 0; r < 4; ++r)
      sO[s * 16 + lh * 4 + r][wave * 16 + l15] = O[s][r] * inv;
  __syncthreads();
  {
    const int c2 = t >> 2, q = t & 3;
    s16x8 v0, v1;
#pragma unroll
    for (int j = 0; j < 8; ++j) v0[j] = (short)f2bf(sO[c2][q * 16 + j]);
#pragma unroll
    for (int j = 0; j < 8; ++j) v1[j] = (short)f2bf(sO[c2][q * 16 + 8 + j]);
    unsigned short* dst = attn + ((size_t)b * 64 + c2) * 4096 + m0 + q * 16;
    *(s16x8*)dst = v0;
    *(s16x8*)(dst + 8) = v1;
  }
}

// ---------------------------------------------------------------------------
// Kernel 3: out = lrelu(W4 @ attn + b4) + x   (fp32 out, [b][c][n])
// grid 256 (b*64 + nchunk), block 256.
// ---------------------------------------------------------------------------
__global__ __launch_bounds__(256) void k3_conv4(
    const unsigned short* __restrict__ attn,
    const float* __restrict__ x,
    const float* __restrict__ W4, const float* __restrict__ b4,
    float* __restrict__ out) {
  __shared__ alignas(16) float Wt[64][68];          // Wt[k][c] = W4[c][k]
  __shared__ alignas(16) unsigned short sA[64][72]; // sA[k][n']
  const int t = threadIdx.x;
  const int b = blockIdx.x >> 6;
  const int n0 = (blockIdx.x & 63) << 6;
  for (int e = t; e < 4096; e += 256)
    Wt[e & 63][e >> 6] = W4[(e >> 6) * 64 + (e & 63)];
  {
    const int k = t >> 2, q = t & 3;
    const unsigned short* src = attn + ((size_t)b * 64 + k) * 4096 + n0 + q * 16;
    *(s16x8*)&sA[k][q * 16] = *(const s16x8*)src;
    *(s16x8*)&sA[k][q * 16 + 8] = *(const s16x8*)(src + 8);
  }
  __syncthreads();
  const int cb = (t >> 4) << 2; // 4 channels per thread
  const int nl = t & 15;        // 4 n's per thread (nj*16 + nl)
  float acc[4][4];
#pragma unroll
  for (int ci = 0; ci < 4; ++ci) {
    const float bias = b4[cb + ci];
#pragma unroll
    for (int nj = 0; nj < 4; ++nj) acc[ci][nj] = bias;
  }
  for (int k = 0; k < 64; ++k) {
    const float4 wv = *(const float4*)&Wt[k][cb];
    float av[4];
#pragma unroll
    for (int nj = 0; nj < 4; ++nj) av[nj] = bf2f(sA[k][nj * 16 + nl]);
#pragma unroll
    for (int ci = 0; ci < 4; ++ci)
#pragma unroll
      for (int nj = 0; nj < 4; ++nj)
        acc[ci][nj] = __builtin_fmaf(((const float*)&wv)[ci], av[nj], acc[ci][nj]);
  }
#pragma unroll
  for (int ci = 0; ci < 4; ++ci)
#pragma unroll
    for (int nj = 0; nj < 4; ++nj) {
      const size_t idx = ((size_t)b * 64 + cb + ci) * 4096 + n0 + nj * 16 + nl;
      out[idx] = lrelu(acc[ci][nj]) + x[idx];
    }
}

extern "C" void kernel_launch(void* const* d_in, const int* in_sizes, int n_in,
                              void* d_out, int out_size, void* d_ws, size_t ws_size,
                              hipStream_t stream) {
  const float* x = (const float*)d_in[0];
  const float* W1 = (const float*)d_in[1];
  const float* b1 = (const float*)d_in[2];
  const float* W2 = (const float*)d_in[3];
  const float* b2 = (const float*)d_in[4];
  const float* W3 = (const float*)d_in[5];
  const float* b3 = (const float*)d_in[6];
  const float* W4 = (const float*)d_in[7];
  const float* b4 = (const float*)d_in[8];
  float* out = (float*)d_out;

  const size_t planes = (size_t)4 * 4096 * 64; // 1M bf16 elems each
  unsigned short* x1t = (unsigned short*)d_ws;
  unsigned short* x2t = x1t + planes;
  unsigned short* x3 = x2t + planes;
  unsigned short* attn = x3 + planes;

  hipLaunchKernelGGL(k1_conv3, dim3(256), dim3(256), 0, stream,
                     x, W1, b1, W2, b2, W3, b3, x1t, x2t, x3);
  hipLaunchKernelGGL(k2_attn, dim3(256), dim3(256), 0, stream, x1t, x2t, x3, attn);
  hipLaunchKernelGGL(k3_conv4, dim3(256), dim3(256), 0, stream, attn, x, W4, b4, out);
}